// Round 5
// baseline (68.253 us; speedup 1.0000x reference)
//
#include <hip/hip_runtime.h>

// Problem constants (match reference)
#define NB 16      // BATCH
#define NC 32      // IN_CH
#define NO 32      // OUT_CH
#define NM 1024    // NODES
#define SEGS 32
#define WLEN 97    // (N-1)*SEGMENTS + 1
#define MT 8       // m-nodes per block

// ---------------------------------------------------------------------------
// Repack w[o][c][0..96] -> w3[c][seg][o] = float4{ w[o][c][3seg .. 3seg+3] }
// 32*32*32 float4 = 512 KB. o innermost: main kernel's gather is coalesced
// (32 lanes x 16B = one contiguous 512B row per (c,seg)).
// ---------------------------------------------------------------------------
__global__ __launch_bounds__(256) void repack_w_kernel(const float* __restrict__ w,
                                                       float4* __restrict__ w3) {
    int i = blockIdx.x * blockDim.x + threadIdx.x;   // 0 .. 32767
    if (i >= NC * SEGS * NO) return;
    int o   = i & 31;
    int seg = (i >> 5) & 31;
    int c   = i >> 10;
    const float* p = w + (o * NC + c) * WLEN + 3 * seg;
    w3[i] = make_float4(p[0], p[1], p[2], p[3]);
}

__device__ __forceinline__ float4 lagrange_basis(float xv, int& id_out) {
    // id = clip(trunc((x+1)/2*32), 0, 31); (x+1)*16 is bit-exact equal.
    float v  = (xv + 1.0f) * 16.0f;
    int   id = (int)v;                 // trunc-toward-zero == astype(int32)
    id = min(max(id, 0), SEGS - 1);
    // x_in = 32*(x - x_min) - 1, x_min = id/16 - 1 (exact)
    const float x_min = (float)id * 0.0625f - 1.0f;
    const float t     = (xv - x_min) * 32.0f - 1.0f;
    // Lagrange basis at Chebyshev points X = {-1, -0.5, 0.5, 1}
    const float d0 = t + 1.0f;
    const float d1 = t + 0.5f;
    const float d2 = t - 0.5f;
    const float d3 = t - 1.0f;
    float4 bb;
    bb.x = d1 * d2 * d3 * (-0.66666667f);  // denom -1.5
    bb.y = d0 * d2 * d3 * ( 1.33333333f);  // denom  0.75
    bb.z = d0 * d1 * d3 * (-1.33333333f);  // denom -0.75
    bb.w = d0 * d1 * d2 * ( 0.66666667f);  // denom  1.5
    id_out = id;
    return bb;
}

// ---------------------------------------------------------------------------
// Main kernel. Block = (b, tile of 8 nodes), 256 threads = 4 waves.
// 2048 blocks -> 8192 waves = 8 waves/SIMD (max TLP for latency hiding).
// Phase 1: 32c x 8m basis + w3 row offset into LDS (1 entry per thread).
// Phase 2: thread = (o = tid&31, mt = tid>>5). Hoist the 32 row offsets
//          into registers (8x ds_read_b128), then fully-unrolled c-loop:
//          1 LDS b128 basis broadcast + 1 coalesced dwordx4 + 4 FMA.
// ---------------------------------------------------------------------------
__global__ __launch_bounds__(256) void pw_main_kernel(const float* __restrict__ x,
                                                      const float4* __restrict__ w3,
                                                      float* __restrict__ out) {
    const int blk = blockIdx.x;          // 0 .. 2047
    const int b   = blk >> 7;            // 16 batches
    const int m0  = (blk & 127) * MT;    // node-tile base

    __shared__ float4 sb[NC][MT];        // basis [c][mt], 4 KB
    __shared__ int    soff[MT][36];      // w3 row offsets [mt][c], padded row

    const int tid = threadIdx.x;

    // ---- phase 1: basis + weight-row offset, one (c,mt) per thread
    {
        const int c  = tid >> 3;
        const int mt = tid & 7;
        const float xv = x[(b * NC + c) * NM + m0 + mt];
        int id;
        float4 bb = lagrange_basis(xv, id);
        sb[c][mt]   = bb;
        soff[mt][c] = (c * SEGS + id) * NO;   // float4-element offset of row
    }
    __syncthreads();

    // ---- phase 2: one output per thread; o innermost across lanes
    const int o  = tid & 31;
    const int mt = tid >> 5;

    // hoist all 32 row offsets into registers (kills per-iter LDS dep chain)
    int4 offs[8];
    {
        const int4* sp = (const int4*)&soff[mt][0];
#pragma unroll
        for (int k = 0; k < 8; ++k) offs[k] = sp[k];
    }

    const float4* __restrict__ wp = w3 + o;

    float acc = 0.0f;
#pragma unroll
    for (int k = 0; k < 8; ++k) {
        const int4 o4 = offs[k];
#pragma unroll
        for (int j = 0; j < 4; ++j) {
            const int c    = 4 * k + j;
            const int base = (j == 0) ? o4.x : (j == 1) ? o4.y : (j == 2) ? o4.z : o4.w;
            const float4 bb = sb[c][mt];   // 32-lane same-address broadcast
            const float4 wv = wp[base];    // 32 lanes x 16B = 512B contiguous
            acc = fmaf(bb.x, wv.x, acc);
            acc = fmaf(bb.y, wv.y, acc);
            acc = fmaf(bb.z, wv.z, acc);
            acc = fmaf(bb.w, wv.w, acc);
        }
    }

    out[(b * NO + o) * NM + m0 + mt] = acc;
}

// ---------------------------------------------------------------------------
// Fallback (ws too small): one thread per output, direct gather from w.
// ---------------------------------------------------------------------------
__global__ __launch_bounds__(256) void pw_fallback_kernel(const float* __restrict__ x,
                                                          const float* __restrict__ w,
                                                          float* __restrict__ out) {
    const int blk = blockIdx.x;          // 0 .. 2047
    const int b   = blk >> 7;
    const int m   = (blk & 127) * 8 + (threadIdx.x & 7);
    const int o   = threadIdx.x >> 3;

    float acc = 0.0f;
    for (int c = 0; c < NC; ++c) {
        const float xv = x[(b * NC + c) * NM + m];
        int id;
        float4 bb = lagrange_basis(xv, id);
        const float* p = w + (o * NC + c) * WLEN + 3 * id;
        acc = fmaf(bb.x, p[0], acc);
        acc = fmaf(bb.y, p[1], acc);
        acc = fmaf(bb.z, p[2], acc);
        acc = fmaf(bb.w, p[3], acc);
    }
    out[(b * NO + o) * NM + m] = acc;
}

extern "C" void kernel_launch(void* const* d_in, const int* in_sizes, int n_in,
                              void* d_out, int out_size, void* d_ws, size_t ws_size,
                              hipStream_t stream) {
    const float* x = (const float*)d_in[0];   // (16, 32, 1024)
    const float* w = (const float*)d_in[1];   // (32, 32, 97)
    float* out = (float*)d_out;               // (16, 32, 1024)

    const size_t w3_bytes = (size_t)NC * SEGS * NO * sizeof(float4);  // 512 KB

    if (ws_size >= w3_bytes) {
        float4* w3 = (float4*)d_ws;
        repack_w_kernel<<<(NC * SEGS * NO + 255) / 256, 256, 0, stream>>>(w, w3);
        pw_main_kernel<<<NB * (NM / MT), 256, 0, stream>>>(x, w3, out);
    } else {
        pw_fallback_kernel<<<NB * (NM / 8), 256, 0, stream>>>(x, w, out);
    }
}

// Round 6
// 64.662 us; speedup vs baseline: 1.0555x; 1.0555x over previous
//
#include <hip/hip_runtime.h>

// Problem constants (match reference)
#define NB 16      // BATCH
#define NC 32      // IN_CH
#define NO 32      // OUT_CH
#define NM 1024    // NODES
#define SEGS 32
#define WLEN 97    // (N-1)*SEGMENTS + 1
#define MTB 64     // m-nodes per block

// LDS layout (dynamic, 148 KB):
//   [0, 131072)            uint2 wlds[16][32][32]   weights for current c-phase (bf16x4)
//   [131072, 147456)       float4 blds[16][64]      basis for current c-phase
//   [147456, 151552)       int   slds[64][16]       byte-offset of weight row, m-major
//   overlay [131072, ...)  float alds[32][66]       epilogue accumulator transpose
#define WLDS_BYTES   131072
#define BLDS_BYTES   16384
#define SLDS_BYTES   4096
#define SMEM_BYTES   (WLDS_BYTES + BLDS_BYTES + SLDS_BYTES)   // 151552

// round-to-nearest-even fp32 -> bf16 (as uint16 in low bits)
__device__ __forceinline__ unsigned f2bf(float f) {
    unsigned u = __float_as_uint(f);
    return (u + 0x7fffu + ((u >> 16) & 1u)) >> 16;
}

// ---------------------------------------------------------------------------
// Repack w[o][c][0..96] -> w4[c][seg][o] = bf16x4{ w[o][c][3seg .. 3seg+3] }
// 32*32*32 * 8B = 256 KB.
// ---------------------------------------------------------------------------
__global__ __launch_bounds__(256) void repack_w_kernel(const float* __restrict__ w,
                                                       uint2* __restrict__ w4) {
    int i = blockIdx.x * blockDim.x + threadIdx.x;   // 0 .. 32767
    if (i >= NC * SEGS * NO) return;
    int o   = i & 31;
    int seg = (i >> 5) & 31;
    int c   = i >> 10;
    const float* p = w + (o * NC + c) * WLEN + 3 * seg;
    unsigned b0 = f2bf(p[0]);
    unsigned b1 = f2bf(p[1]);
    unsigned b2 = f2bf(p[2]);
    unsigned b3 = f2bf(p[3]);
    w4[i] = make_uint2(b0 | (b1 << 16), b2 | (b3 << 16));
}

__device__ __forceinline__ float4 lagrange_basis(float xv, int& id_out) {
    // id = clip(trunc((x+1)/2*32), 0, 31); (x+1)*16 is bit-exact equal.
    float v  = (xv + 1.0f) * 16.0f;
    int   id = (int)v;                 // trunc-toward-zero == astype(int32)
    id = min(max(id, 0), SEGS - 1);
    // x_in = 32*(x - x_min) - 1, x_min = id/16 - 1 (exact)
    const float x_min = (float)id * 0.0625f - 1.0f;
    const float t     = (xv - x_min) * 32.0f - 1.0f;
    // Lagrange basis at Chebyshev points X = {-1, -0.5, 0.5, 1}
    const float d0 = t + 1.0f;
    const float d1 = t + 0.5f;
    const float d2 = t - 0.5f;
    const float d3 = t - 1.0f;
    float4 bb;
    bb.x = d1 * d2 * d3 * (-0.66666667f);  // denom -1.5
    bb.y = d0 * d2 * d3 * ( 1.33333333f);  // denom  0.75
    bb.z = d0 * d1 * d3 * (-1.33333333f);  // denom -0.75
    bb.w = d0 * d1 * d2 * ( 0.66666667f);  // denom  1.5
    id_out = id;
    return bb;
}

// ---------------------------------------------------------------------------
// Main kernel: 256 blocks (1/CU) x 1024 threads (16 waves/CU).
// Block = (b, 64-node tile). Two c-phases (c 0-15, 16-31):
//   stage 128 KB weights -> LDS, compute basis+segoff -> LDS, barrier,
//   then per thread (o = tid&31, mslot = tid>>5, m in {mslot, mslot+32}):
//   16 c-iters x { ds_read_b64 weight row gather (conflict-free),
//                  basis b128 broadcast, bf16 expand, 4 FMA } per m.
// Epilogue: transpose acc via padded LDS, coalesced dwordx2 out-write.
// ---------------------------------------------------------------------------
__global__ __launch_bounds__(1024, 4) void pw_main_kernel(const float* __restrict__ x,
                                                          const uint2* __restrict__ w4,
                                                          float* __restrict__ out) {
    extern __shared__ char smem[];
    uint2*  wlds = (uint2*)smem;
    float4* blds = (float4*)(smem + WLDS_BYTES);
    int*    slds = (int*)(smem + WLDS_BYTES + BLDS_BYTES);
    float*  alds = (float*)(smem + WLDS_BYTES);       // epilogue overlay

    const int blk = blockIdx.x;          // 0 .. 255
    const int b   = blk >> 4;            // 16 batches
    const int m0  = (blk & 15) * MTB;    // node-tile base

    const int t     = threadIdx.x;
    const int o     = t & 31;
    const int mslot = t >> 5;            // 0..31; handles m = mslot, mslot+32

    float acc0 = 0.0f, acc1 = 0.0f;

#pragma unroll
    for (int p = 0; p < 2; ++p) {
        if (p) __syncthreads();          // prev-phase gathers done before overwrite

        // ---- stage 128 KB of weights: 8192 uint4, 8 per thread, coalesced
        {
            const uint4* src = (const uint4*)(w4 + (size_t)p * 16 * SEGS * NO);
            uint4* dst = (uint4*)wlds;
#pragma unroll
            for (int k = 0; k < 8; ++k) dst[t + 1024 * k] = src[t + 1024 * k];
        }

        // ---- basis + segment byte-offset for the 16 c's of this phase
        {
            const int cp = t >> 6;       // 0..15
            const int m  = t & 63;
            const float xv = x[(b * NC + p * 16 + cp) * NM + m0 + m];
            int id;
            float4 bb = lagrange_basis(xv, id);
            blds[cp * 64 + m] = bb;
            slds[m * 16 + cp] = ((cp * SEGS + id) * NO) * 8;  // byte offset in wlds
        }
        __syncthreads();

        // ---- hoist this thread's 32 row offsets (2 m's x 16 c) into registers
        int4 offA[4], offB[4];
        {
            const int4* s0 = (const int4*)&slds[mslot * 16];
            const int4* s1 = (const int4*)&slds[(mslot + 32) * 16];
#pragma unroll
            for (int k = 0; k < 4; ++k) { offA[k] = s0[k]; offB[k] = s1[k]; }
        }

        const char* wb = (const char*)wlds;
#pragma unroll
        for (int k = 0; k < 4; ++k) {
            const int4 oa = offA[k];
            const int4 ob = offB[k];
#pragma unroll
            for (int j = 0; j < 4; ++j) {
                const int cp = 4 * k + j;
                const int ba = (j == 0) ? oa.x : (j == 1) ? oa.y : (j == 2) ? oa.z : oa.w;
                const int bbo = (j == 0) ? ob.x : (j == 1) ? ob.y : (j == 2) ? ob.z : ob.w;
                const float4 B0 = blds[cp * 64 + mslot];        // 32-lane broadcast
                const float4 B1 = blds[cp * 64 + mslot + 32];
                const uint2 pa = *(const uint2*)(wb + ba + o * 8);   // conflict-free
                const uint2 pb = *(const uint2*)(wb + bbo + o * 8);
                acc0 = fmaf(B0.x, __uint_as_float(pa.x << 16), acc0);
                acc0 = fmaf(B0.y, __uint_as_float(pa.x & 0xffff0000u), acc0);
                acc0 = fmaf(B0.z, __uint_as_float(pa.y << 16), acc0);
                acc0 = fmaf(B0.w, __uint_as_float(pa.y & 0xffff0000u), acc0);
                acc1 = fmaf(B1.x, __uint_as_float(pb.x << 16), acc1);
                acc1 = fmaf(B1.y, __uint_as_float(pb.x & 0xffff0000u), acc1);
                acc1 = fmaf(B1.z, __uint_as_float(pb.y << 16), acc1);
                acc1 = fmaf(B1.w, __uint_as_float(pb.y & 0xffff0000u), acc1);
            }
        }
    }

    // ---- epilogue: transpose via padded LDS, coalesced out-write
    __syncthreads();                     // all gathers done; overlay alds on blds
    alds[o * 66 + mslot]      = acc0;    // 2 lanes/bank: free
    alds[o * 66 + mslot + 32] = acc1;
    __syncthreads();
    {
        const int o2 = t >> 5;           // 0..31
        const int mw = t & 31;           // handles m = 2mw, 2mw+1
        float2 r;
        r.x = alds[o2 * 66 + 2 * mw];
        r.y = alds[o2 * 66 + 2 * mw + 1];
        *(float2*)&out[(b * NO + o2) * NM + m0 + 2 * mw] = r;
    }
}

// ---------------------------------------------------------------------------
// Fallback (ws too small): one thread per output, direct gather from w.
// ---------------------------------------------------------------------------
__global__ __launch_bounds__(256) void pw_fallback_kernel(const float* __restrict__ x,
                                                          const float* __restrict__ w,
                                                          float* __restrict__ out) {
    const int blk = blockIdx.x;          // 0 .. 2047
    const int b   = blk >> 7;
    const int m   = (blk & 127) * 8 + (threadIdx.x & 7);
    const int o   = threadIdx.x >> 3;

    float acc = 0.0f;
    for (int c = 0; c < NC; ++c) {
        const float xv = x[(b * NC + c) * NM + m];
        int id;
        float4 bb = lagrange_basis(xv, id);
        const float* p = w + (o * NC + c) * WLEN + 3 * id;
        acc = fmaf(bb.x, p[0], acc);
        acc = fmaf(bb.y, p[1], acc);
        acc = fmaf(bb.z, p[2], acc);
        acc = fmaf(bb.w, p[3], acc);
    }
    out[(b * NO + o) * NM + m] = acc;
}

extern "C" void kernel_launch(void* const* d_in, const int* in_sizes, int n_in,
                              void* d_out, int out_size, void* d_ws, size_t ws_size,
                              hipStream_t stream) {
    const float* x = (const float*)d_in[0];   // (16, 32, 1024)
    const float* w = (const float*)d_in[1];   // (32, 32, 97)
    float* out = (float*)d_out;               // (16, 32, 1024)

    const size_t w4_bytes = (size_t)NC * SEGS * NO * sizeof(uint2);  // 256 KB

    static bool attr_set = false;  // idempotent attribute; setting every call is also fine
    (void)attr_set;
    hipError_t err = hipFuncSetAttribute((const void*)pw_main_kernel,
                                         hipFuncAttributeMaxDynamicSharedMemorySize,
                                         SMEM_BYTES);

    if (err == hipSuccess && ws_size >= w4_bytes) {
        uint2* w4 = (uint2*)d_ws;
        repack_w_kernel<<<(NC * SEGS * NO + 255) / 256, 256, 0, stream>>>(w, w4);
        pw_main_kernel<<<NB * (NM / MTB), 1024, SMEM_BYTES, stream>>>(x, w4, out);
    } else {
        pw_fallback_kernel<<<NB * (NM / 8), 256, 0, stream>>>(x, w, out);
    }
}